// Round 12
// baseline (498.135 us; speedup 1.0000x reference)
//
#include <hip/hip_runtime.h>
#include <math.h>

#define S_LEN 2048
#define HIDD  2048
#define NHEAD 16
#define HD    128

// Tiled plane layout for all GEMM operands: plane = [rt][kt][128][32] bf16,
// tile = 8 KB contiguous. rt = row/128 (16 tiles), kt = k/32 (64 tiles).
#define TILE_SH 4096   // shorts per tile

typedef __attribute__((ext_vector_type(8))) short short8;
typedef __attribute__((ext_vector_type(4))) float float4v;
typedef unsigned short ushort_t;

static __device__ __forceinline__ ushort_t f2bf(float f) {
    unsigned int u = __float_as_uint(f);
    u += 0x7fff + ((u >> 16) & 1);
    return (ushort_t)(u >> 16);
}
static __device__ __forceinline__ float bf2f(ushort_t s) {
    return __uint_as_float(((unsigned int)s) << 16);
}
__device__ __forceinline__ float silu_f(float x) { return x / (1.f + expf(-x)); }

__device__ __forceinline__ void gl_lds16(const ushort_t* g, short* l) {
    __builtin_amdgcn_global_load_lds((const __attribute__((address_space(1))) void*)g,
                                     (__attribute__((address_space(3))) void*)l, 16, 0, 0);
}

// fp32 row-major -> (hi, lo) TILED bf16 planes
__global__ __launch_bounds__(256)
void split_kernel(const float* __restrict__ in, ushort_t* __restrict__ hi,
                  ushort_t* __restrict__ lo, int n4)
{
    const int i = blockIdx.x * 256 + threadIdx.x;
    if (i >= n4) return;
    const float4 v = ((const float4*)in)[i];
    ushort4 h, l;
    h.x = f2bf(v.x); l.x = f2bf(v.x - bf2f(h.x));
    h.y = f2bf(v.y); l.y = f2bf(v.y - bf2f(h.y));
    h.z = f2bf(v.z); l.z = f2bf(v.z - bf2f(h.z));
    h.w = f2bf(v.w); l.w = f2bf(v.w - bf2f(h.w));
    const int row = i >> 9, c4 = (i & 511) * 4;      // 512 float4 per 2048-row
    const size_t off = ((size_t)((row >> 7) * 64 + (c4 >> 5))) * TILE_SH
                     + (row & 127) * 32 + (c4 & 31);
    *(ushort4*)&hi[off] = h;
    *(ushort4*)&lo[off] = l;
}

// out += p0 + p1 + p2 (final reduction for MODE-1 split-K=4; p strided by n4 float4s)
__global__ __launch_bounds__(256)
void addp_kernel(float* __restrict__ out, const float* __restrict__ p, int n4)
{
    const int i = blockIdx.x * 256 + threadIdx.x;
    if (i >= n4) return;
    float4 a = ((const float4*)out)[i];
    const float4 b0 = ((const float4*)p)[i];
    const float4 b1 = ((const float4*)p)[i + n4];
    const float4 b2 = ((const float4*)p)[i + 2 * n4];
    a.x += b0.x + b1.x + b2.x;
    a.y += b0.y + b1.y + b2.y;
    a.z += b0.z + b1.z + b2.z;
    a.w += b0.w + b1.w + b2.w;
    ((float4*)out)[i] = a;
}

// All 5 weights W (K x N f32) -> WT hi/lo (N x K bf16), TILED.
__global__ __launch_bounds__(256)
void split_transpose_all(const float* __restrict__ W0, const float* __restrict__ W1,
                         const float* __restrict__ W2, const float* __restrict__ W3,
                         const float* __restrict__ W4, ushort_t* __restrict__ wt)
{
    __shared__ float t[64][65];
    const size_t PL = (size_t)HIDD * HIDD;
    const int z = blockIdx.z;
    const float* W = (z == 0) ? W0 : (z == 1) ? W1 : (z == 2) ? W2 : (z == 3) ? W3 : W4;
    ushort_t* Thi = wt + (size_t)z * 2 * PL;
    ushort_t* Tlo = Thi + PL;

    const int k0 = blockIdx.y * 64, n0 = blockIdx.x * 64;
    const int tx = threadIdx.x & 15, ty = threadIdx.x >> 4;
    #pragma unroll
    for (int it = 0; it < 4; it++) {
        const int k = ty + it * 16;
        const float4 v = *(const float4*)&W[(size_t)(k0 + k) * HIDD + n0 + tx * 4];
        t[k][tx * 4 + 0] = v.x; t[k][tx * 4 + 1] = v.y;
        t[k][tx * 4 + 2] = v.z; t[k][tx * 4 + 3] = v.w;
    }
    __syncthreads();
    #pragma unroll
    for (int it = 0; it < 4; it++) {
        const int n = ty + it * 16;
        ushort4 h, l; float a;
        a = t[tx * 4 + 0][n]; h.x = f2bf(a); l.x = f2bf(a - bf2f(h.x));
        a = t[tx * 4 + 1][n]; h.y = f2bf(a); l.y = f2bf(a - bf2f(h.y));
        a = t[tx * 4 + 2][n]; h.z = f2bf(a); l.z = f2bf(a - bf2f(h.z));
        a = t[tx * 4 + 3][n]; h.w = f2bf(a); l.w = f2bf(a - bf2f(h.w));
        const int nn_ = n0 + n, kk_ = k0 + tx * 4;
        const size_t off = ((size_t)((nn_ >> 7) * 64 + (kk_ >> 5))) * TILE_SH
                         + (nn_ & 127) * 32 + (kk_ & 31);
        *(ushort4*)&Thi[off] = h;
        *(ushort4*)&Tlo[off] = l;
    }
}

// Split-bf16 MFMA GEMM, 128x128 tile, BK=32, 16x16x32 MFMA, A+B in LDS,
// single-buffer 2-sync K-loop (the best-measured regime across r7-r11:
// 32 KB LDS + grid-1024 residency; dbuf/A-from-global variants all measured
// slower — see r3/r8/r10 post-mortems).
// r12: MODE 1 moved into the same regime — split-K=4, grid 1024 (kh=lin>>8,
// 16 kt each): kh=0 -> outC, kh=1..3 -> partial fp32 planes; addp sums 3.
// MODE 0: x @ [WqT|WkT|WvT|WgT]; q/k xpos -> bf16 hi/lo [h][s][d]; v -> transposed
//         bf16 hi/lo [h][d][s]; g -> fp32 [s][2048]. Grid 1024 (XCD n-groups).
template<int MODE>
__global__ __launch_bounds__(256, 4)
void mfma_gemm(const ushort_t* __restrict__ Ahi, const ushort_t* __restrict__ Alo,
               const ushort_t* __restrict__ WT, const int* __restrict__ pos_ids,
               ushort_t* __restrict__ qhi, ushort_t* __restrict__ qlo,
               ushort_t* __restrict__ khi, ushort_t* __restrict__ klo,
               ushort_t* __restrict__ vThi, ushort_t* __restrict__ vTlo,
               float* __restrict__ gbuf, float* __restrict__ outC)
{
    __shared__ __align__(16) short sm[16384];   // 4 planes x 8 KB = 32 KB

    const int tid = threadIdx.x;
    const int w = tid >> 6, L = tid & 63;
    const int qd = L >> 4, lc = L & 15;
    const int lin = blockIdx.x;
    int n0, m0, kh = 0;
    if (MODE == 0) {   // XCD-stable n-groups: XCD (lin&7 heuristic) sees n-tiles 8j..8j+7
        n0 = (((lin & 7) << 3) + ((lin >> 3) & 7)) << 7;
        m0 = (lin >> 6) << 7;
    } else {
        n0 = (lin & 15) << 7;
        m0 = ((lin >> 4) & 15) << 7;
        kh = lin >> 8;                  // 0..3
    }
    const size_t PL = (size_t)HIDD * HIDD;

    int sel, nn;
    const ushort_t *Bhi, *Blo;
    if (MODE == 0) {
        sel = n0 >> 11; nn = n0 & 2047;
        Bhi = WT + (size_t)sel * 2 * PL; Blo = Bhi + PL;
    } else {
        sel = -1; nn = n0;
        Bhi = WT; Blo = WT + PL;
    }

    // wave w stages plane w: 0:Ahi 1:Alo 2:Bhi 3:Blo
    const ushort_t* pbase = (w == 0) ? Ahi : (w == 1) ? Alo : (w == 2) ? Bhi : Blo;
    const int rt = ((w < 2) ? m0 : nn) >> 7;
    const ushort_t* tb0 = pbase + (size_t)rt * 64 * TILE_SH + L * 8;
    short* ldsw = sm + w * 4096;

    const int wm = (w & 1) * 64, wn = (w >> 1) * 64;
    int aoff[4], boff[4];
    #pragma unroll
    for (int i = 0; i < 4; i++) aoff[i] = (wm + i * 16 + lc) * 32 + qd * 8;
    #pragma unroll
    for (int j = 0; j < 4; j++) boff[j] = (wn + j * 16 + lc) * 32 + qd * 8;

    float4v acc[4][4];
    #pragma unroll
    for (int i = 0; i < 4; i++)
        #pragma unroll
        for (int j = 0; j < 4; j++)
            #pragma unroll
            for (int r = 0; r < 4; r++) acc[i][j][r] = 0.f;

    const int kt0 = (MODE == 1) ? kh * 16 : 0;
    const int kt1 = (MODE == 1) ? kt0 + 16 : 64;

    // single buffer: stage -> sync -> compute -> sync (best-measured loop).
    for (int kt = kt0; kt < kt1; kt++) {
        const ushort_t* g = tb0 + (size_t)kt * TILE_SH;
        #pragma unroll
        for (int t = 0; t < 8; t++)
            gl_lds16(g + t * 512, ldsw + t * 512);
        __syncthreads();

        short8 bhf[4], blf[4];
        #pragma unroll
        for (int j = 0; j < 4; j++) {
            bhf[j] = *(const short8*)(sm + 8192  + boff[j]);
            blf[j] = *(const short8*)(sm + 12288 + boff[j]);
        }
        #pragma unroll
        for (int i = 0; i < 4; i++) {
            const short8 ahf = *(const short8*)(sm + aoff[i]);
            const short8 alf = *(const short8*)(sm + 4096 + aoff[i]);
            #pragma unroll
            for (int j = 0; j < 4; j++) {
                acc[i][j] = __builtin_amdgcn_mfma_f32_16x16x32_bf16(ahf, bhf[j], acc[i][j], 0, 0, 0);
                acc[i][j] = __builtin_amdgcn_mfma_f32_16x16x32_bf16(alf, bhf[j], acc[i][j], 0, 0, 0);
                acc[i][j] = __builtin_amdgcn_mfma_f32_16x16x32_bf16(ahf, blf[j], acc[i][j], 0, 0, 0);
            }
        }
        __syncthreads();
    }

    // ---- epilogue via LDS bounce; stores 16B/lane wave-contiguous.
    float* ob = (float*)sm;              // [32][132]
    const int half = w & 1;
    const int head = nn >> 7;

    // #pragma unroll REQUIRED (rule #20): runtime i would put acc in scratch
    // (r0 evidence: VGPR=64, WRITE_SIZE=3.85GB, MfmaUtil 11%).
    #pragma unroll
    for (int i = 0; i < 4; i++) {
        #pragma unroll
        for (int j = 0; j < 4; j++)
            #pragma unroll
            for (int r = 0; r < 4; r++)
                ob[(half * 16 + qd * 4 + r) * 132 + wn + j * 16 + lc] = acc[i][j][r];
        __syncthreads();

        if (MODE == 1 || sel == 3) {
            float* dst = (MODE == 1) ? ((kh == 0) ? outC : gbuf + (size_t)(kh - 1) * PL)
                                     : gbuf;
            #pragma unroll
            for (int p = 0; p < 4; p++) {
                const int row = p * 8 + (tid >> 5);
                const int c = (tid & 31) * 4;
                const int grow = m0 + (row >> 4) * 64 + i * 16 + (row & 15);
                const float4 vv = *(const float4*)&ob[row * 132 + c];
                *(float4*)&dst[(size_t)grow * HIDD + nn + c] = vv;
            }
        } else if (sel == 2) {
            const int d = tid >> 1, hs = tid & 1;
            const int sbase2 = m0 + hs * 64 + i * 16;
            short8 h0, h1, l0, l1;
            #pragma unroll
            for (int sp = 0; sp < 8; sp++) {
                float a = ob[(hs * 16 + sp) * 132 + d];
                ushort_t hb = f2bf(a);
                h0[sp] = (short)hb; l0[sp] = (short)f2bf(a - bf2f(hb));
                a = ob[(hs * 16 + 8 + sp) * 132 + d];
                hb = f2bf(a);
                h1[sp] = (short)hb; l1[sp] = (short)f2bf(a - bf2f(hb));
            }
            ushort_t* dh = vThi + ((size_t)head * HD + d) * S_LEN + sbase2;
            ushort_t* dl = vTlo + ((size_t)head * HD + d) * S_LEN + sbase2;
            *(short8*)dh = h0; *(short8*)(dh + 8) = h1;
            *(short8*)dl = l0; *(short8*)(dl + 8) = l1;
        } else {
            const float sgn = (sel == 0) ? 1.f : -1.f;
            ushort_t* dhb = (sel == 0) ? qhi : khi;
            ushort_t* dlb = (sel == 0) ? qlo : klo;
            #pragma unroll
            for (int p = 0; p < 2; p++) {
                const int row = p * 16 + (tid >> 4);
                const int c8 = (tid & 15) * 8;
                const int grow = m0 + (row >> 4) * 64 + i * 16 + (row & 15);
                const float pos = (float)pos_ids[grow];
                const float pe = sgn * pos * (1.f / 512.f);
                short8 hv, lv;
                #pragma unroll
                for (int pp = 0; pp < 4; pp++) {
                    const int d = c8 + pp * 2;
                    const float v0 = ob[row * 132 + d], v1 = ob[row * 132 + d + 1];
                    const float invf = exp2f(-(float)d * (13.28771238f / 128.f));
                    float s, c_; sincosf(pos * invf, &s, &c_);
                    const float scl = exp2f(log2f(((float)d + 51.2f) * (1.f / 179.2f)) * pe);
                    const float e0 = (v0 * c_ - v1 * s) * scl;
                    const float e1 = (v1 * c_ + v0 * s) * scl;
                    const ushort_t h0 = f2bf(e0), h1 = f2bf(e1);
                    hv[pp * 2] = (short)h0;  hv[pp * 2 + 1] = (short)h1;
                    lv[pp * 2] = (short)f2bf(e0 - bf2f(h0));
                    lv[pp * 2 + 1] = (short)f2bf(e1 - bf2f(h1));
                }
                *(short8*)&dhb[((size_t)head * S_LEN + grow) * HD + c8] = hv;
                *(short8*)&dlb[((size_t)head * S_LEN + grow) * HD + c8] = lv;
            }
        }
        __syncthreads();
    }
}

// Retention core: MFMA QK^T -> decay -> P relayout -> MFMA PV -> partial osum
// to global. Triangular-workload balance (r9): work unit = (head, qb, part);
// 768 blocks = 3/CU, big-work-first, GN/silu/y-pack in gn_epilogue.
#define KROW 136
#define VROW 40
#define KH_  0
#define KL_  (32 * KROW)
#define VH_  (2 * 32 * KROW)
#define VL_  (VH_ + 128 * VROW)
#define PH_  (VH_ + 2 * 128 * VROW)
#define PLO_ (PH_ + 64 * VROW)
__global__ __launch_bounds__(256, 3)
void retention2(const ushort_t* __restrict__ qhi, const ushort_t* __restrict__ qlo,
                const ushort_t* __restrict__ khi, const ushort_t* __restrict__ klo,
                const ushort_t* __restrict__ vThi, const ushort_t* __restrict__ vTlo,
                float* __restrict__ posum)
{
    __shared__ __align__(16) short sm[24064];

    const int bx = blockIdx.x;
    const int h = bx & 15;
    const int u = bx >> 4;          // 0..47, ascending = descending work
    const int g = u / 3, r3 = u % 3;
    int qb, c0, c1, part;
    if (r3 < 2) {                   // halves of qb = 31-g (17..32 chunks each)
        qb = 31 - g; part = r3;
        const int hchunks = qb + 1;
        c0 = r3 * hchunks; c1 = c0 + hchunks;
    } else {                        // whole qb = 15-g (2..32 chunks)
        qb = 15 - g; part = 0;
        c0 = 0; c1 = 2 * (qb + 1);
    }
    const int r0 = qb * 64;
    const int tid = threadIdx.x;
    const int w = tid >> 6, L = tid & 63;
    const int qd = L >> 4, lc = L & 15;

    const float e = -3.4657359f + (float)h * ((-6.2383246f + 3.4657359f) / 15.f);
    const float lg2g = logf(1.f - expf(e)) * 1.44269504f;

    short8 qfh[4], qfl[4];
    {
        const size_t qb0 = ((size_t)h * S_LEN + r0 + w * 16 + lc) * HD + qd * 8;
        #pragma unroll
        for (int ks = 0; ks < 4; ks++) {
            qfh[ks] = *(const short8*)(qhi + qb0 + ks * 32);
            qfl[ks] = *(const short8*)(qlo + qb0 + ks * 32);
        }
    }

    float4v osum[2][4];
    #pragma unroll
    for (int mt = 0; mt < 2; mt++)
        #pragma unroll
        for (int j = 0; j < 4; j++)
            #pragma unroll
            for (int r = 0; r < 4; r++) osum[mt][j][r] = 0.f;

    const int qh_ = w >> 1, vh_ = w & 1;

    for (int ch = c0; ch < c1; ch++) {
        const int kg0 = ch * 32;
        #pragma unroll
        for (int t = 0; t < 4; t++) {
            const int c = t * 256 + tid;
            const int p = c >> 9, r = (c >> 4) & 31, qq = c & 15;
            const ushort_t* src = (p ? klo : khi) + ((size_t)h * S_LEN + kg0 + r) * HD + qq * 8;
            *(short8*)(sm + (p ? KL_ : KH_) + r * KROW + qq * 8) = *(const short8*)src;
        }
        #pragma unroll
        for (int t = 0; t < 4; t++) {
            const int c = t * 256 + tid;
            const int p = c >> 9, r = (c >> 2) & 127, qq = c & 3;
            const ushort_t* src = (p ? vTlo : vThi) + ((size_t)h * HD + r) * S_LEN + kg0 + qq * 8;
            *(short8*)(sm + (p ? VL_ : VH_) + r * VROW + qq * 8) = *(const short8*)src;
        }
        __syncthreads();

        float4v sacc[2];
        #pragma unroll
        for (int j = 0; j < 2; j++)
            #pragma unroll
            for (int r = 0; r < 4; r++) sacc[j][r] = 0.f;
        #pragma unroll
        for (int ks = 0; ks < 4; ks++) {
            #pragma unroll
            for (int j = 0; j < 2; j++) {
                const short8 bh = *(const short8*)(sm + KH_ + (j * 16 + lc) * KROW + ks * 32 + qd * 8);
                const short8 bl = *(const short8*)(sm + KL_ + (j * 16 + lc) * KROW + ks * 32 + qd * 8);
                sacc[j] = __builtin_amdgcn_mfma_f32_16x16x32_bf16(qfh[ks], bh, sacc[j], 0, 0, 0);
                sacc[j] = __builtin_amdgcn_mfma_f32_16x16x32_bf16(qfl[ks], bh, sacc[j], 0, 0, 0);
                sacc[j] = __builtin_amdgcn_mfma_f32_16x16x32_bf16(qfh[ks], bl, sacc[j], 0, 0, 0);
            }
        }
        #pragma unroll
        for (int j = 0; j < 2; j++)
            #pragma unroll
            for (int r = 0; r < 4; r++) {
                const int dq = (r0 + w * 16 + qd * 4 + r) - (kg0 + j * 16 + lc);
                const float p = (dq >= 0) ? sacc[j][r] * exp2f(lg2g * (float)dq) : 0.f;
                const ushort_t hb = f2bf(p);
                const int off = (w * 16 + qd * 4 + r) * VROW + j * 16 + lc;
                sm[PH_ + off]  = (short)hb;
                sm[PLO_ + off] = (short)f2bf(p - bf2f(hb));
            }
        __syncthreads();

        #pragma unroll
        for (int mt = 0; mt < 2; mt++) {
            const short8 pfh = *(const short8*)(sm + PH_  + (qh_ * 32 + mt * 16 + lc) * VROW + qd * 8);
            const short8 pfl = *(const short8*)(sm + PLO_ + (qh_ * 32 + mt * 16 + lc) * VROW + qd * 8);
            #pragma unroll
            for (int j = 0; j < 4; j++) {
                const short8 vfh = *(const short8*)(sm + VH_ + (vh_ * 64 + j * 16 + lc) * VROW + qd * 8);
                const short8 vfl = *(const short8*)(sm + VL_ + (vh_ * 64 + j * 16 + lc) * VROW + qd * 8);
                osum[mt][j] = __builtin_amdgcn_mfma_f32_16x16x32_bf16(pfh, vfh, osum[mt][j], 0, 0, 0);
                osum[mt][j] = __builtin_amdgcn_mfma_f32_16x16x32_bf16(pfl, vfh, osum[mt][j], 0, 0, 0);
                osum[mt][j] = __builtin_amdgcn_mfma_f32_16x16x32_bf16(pfh, vfl, osum[mt][j], 0, 0, 0);
            }
        }
        __syncthreads();
    }

    // partial osum -> global [h][qb][part][64][128] f32
    float* pdst = posum + (((size_t)(h * 32 + qb) * 2 + part) * 8192);
    #pragma unroll
    for (int mt = 0; mt < 2; mt++)
        #pragma unroll
        for (int j = 0; j < 4; j++)
            #pragma unroll
            for (int r = 0; r < 4; r++) {
                const int row = qh_ * 32 + mt * 16 + qd * 4 + r;
                const int col = vh_ * 64 + j * 16 + lc;
                pdst[row * 128 + col] = osum[mt][j][r];
            }
}

// Sum partials -> groupnorm -> silu gate -> y hi/lo TILED planes.
#define EKROW 136
__global__ __launch_bounds__(256, 2)
void gn_epilogue(const float* __restrict__ posum, const float* __restrict__ gbuf,
                 const float* __restrict__ gnw, const float* __restrict__ gnb,
                 ushort_t* __restrict__ yhi, ushort_t* __restrict__ ylo)
{
    __shared__ __align__(16) short sm[2 * 64 * EKROW];
    const int qb = blockIdx.x, h = blockIdx.y;
    const int tid = threadIdx.x;
    const int row = tid >> 2;            // 0..63
    const int cq = (tid & 3) * 32;
    const int grow = qb * 64 + row;
    const float* p0 = posum + ((size_t)(h * 32 + qb) * 2) * 8192 + row * 128;
    const float* p1 = p0 + 8192;
    const bool two = (qb >= 16);

    float v[32];
    float s1 = 0.f, s2 = 0.f;
    #pragma unroll
    for (int c = 0; c < 32; c += 4) {
        float4 a = *(const float4*)&p0[cq + c];
        if (two) {
            const float4 b = *(const float4*)&p1[cq + c];
            a.x += b.x; a.y += b.y; a.z += b.z; a.w += b.w;
        }
        v[c] = a.x; v[c + 1] = a.y; v[c + 2] = a.z; v[c + 3] = a.w;
        s1 += a.x + a.y + a.z + a.w;
        s2 += a.x * a.x + a.y * a.y + a.z * a.z + a.w * a.w;
    }
    s1 += __shfl_xor(s1, 1); s2 += __shfl_xor(s2, 1);
    s1 += __shfl_xor(s1, 2); s2 += __shfl_xor(s2, 2);
    const float mean = s1 * (1.f / 128.f);
    const float inv = 1.f / sqrtf(s2 * (1.f / 128.f) - mean * mean + 1e-5f);

    #pragma unroll
    for (int c = 0; c < 32; c++) {
        const int col = cq + c;
        const float gv = gbuf[(size_t)grow * HIDD + h * HD + col];
        const float o = ((v[c] - mean) * inv * gnw[h * HD + col] + gnb[h * HD + col])
                      * silu_f(gv);
        const ushort_t hb = f2bf(o);
        sm[row * EKROW + col] = (short)hb;
        sm[64 * EKROW + row * EKROW + col] = (short)f2bf(o - bf2f(hb));
    }
    __syncthreads();
    const int r_ = tid >> 2, cs = (tid & 3) * 32;
    const int g2 = qb * 64 + r_;
    const size_t tb = ((size_t)((g2 >> 7) * 64 + h * 4 + (tid & 3))) * TILE_SH
                    + (g2 & 127) * 32;
    #pragma unroll
    for (int c8 = 0; c8 < 4; c8++) {
        *(short8*)(yhi + tb + c8 * 8) = *(const short8*)(sm + r_ * EKROW + cs + c8 * 8);
        *(short8*)(ylo + tb + c8 * 8) = *(const short8*)(sm + 64 * EKROW + r_ * EKROW + cs + c8 * 8);
    }
}

extern "C" void kernel_launch(void* const* d_in, const int* in_sizes, int n_in,
                              void* d_out, int out_size, void* d_ws, size_t ws_size,
                              hipStream_t stream) {
    const float* x   = (const float*)d_in[0];
    const int*   pid = (const int*)d_in[1];
    const float* gnw = (const float*)d_in[7];
    const float* gnb = (const float*)d_in[8];
    float* out = (float*)d_out;
    (void)in_sizes; (void)n_in; (void)out_size; (void)ws_size;

    const size_t PL = (size_t)HIDD * HIDD;

    ushort_t* wt   = (ushort_t*)d_ws;          // 10 tiled planes = 80 MiB
    ushort_t* xhi  = wt + 10 * PL;             // tiled
    ushort_t* xlo  = xhi + PL;
    ushort_t* qhi_ = xlo + PL;                 // row-major [h][s][d]
    ushort_t* qlo_ = qhi_ + PL;
    ushort_t* khi_ = qlo_ + PL;
    ushort_t* klo_ = khi_ + PL;
    ushort_t* vThi = klo_ + PL;                // row-major [h][d][s]
    ushort_t* vTlo = vThi + PL;
    float*    gbuf = (float*)(vTlo + PL);      // row-major fp32
    ushort_t* yhi  = (ushort_t*)(gbuf + PL);   // tiled
    ushort_t* ylo  = yhi + PL;
    // MODE-1 split-K partials: 3 fp32 planes (48 MB) over xhi..klo_
    // (xhi/xlo dead after mfma_gemm<0>; qhi..klo dead after retention2).
    float*    pb   = (float*)xhi;
    // retention partial osum (33.5 MB): wt planes 0..4 (dead after gemm<0>;
    // gemm<1> reads only wt+8PL/wt+9PL).
    float*    posum = (float*)wt;

    split_kernel<<<(int)(PL / 4 / 256), 256, 0, stream>>>(x, xhi, xlo, (int)(PL / 4));
    split_transpose_all<<<dim3(32, 32, 5), 256, 0, stream>>>(
        (const float*)d_in[2], (const float*)d_in[3], (const float*)d_in[4],
        (const float*)d_in[5], (const float*)d_in[6], wt);

    mfma_gemm<0><<<1024, 256, 0, stream>>>(xhi, xlo, wt, pid,
        qhi_, qlo_, khi_, klo_, vThi, vTlo, gbuf, nullptr);

    retention2<<<768, 256, 0, stream>>>(qhi_, qlo_, khi_, klo_, vThi, vTlo, posum);

    gn_epilogue<<<dim3(32, 16), 256, 0, stream>>>(posum, gbuf, gnw, gnb, yhi, ylo);

    mfma_gemm<1><<<1024, 256, 0, stream>>>(yhi, ylo, wt + 8 * PL, pid,
        nullptr, nullptr, nullptr, nullptr, nullptr, nullptr, pb, out);

    addp_kernel<<<(int)(PL / 4 / 256), 256, 0, stream>>>(out, pb, (int)(PL / 4));
}

// Round 13
// 493.108 us; speedup vs baseline: 1.0102x; 1.0102x over previous
//
#include <hip/hip_runtime.h>
#include <math.h>

#define S_LEN 2048
#define HIDD  2048
#define NHEAD 16
#define HD    128

// Tiled plane layout for all GEMM operands: plane = [rt][kt][128][32] bf16,
// tile = 8 KB contiguous. rt = row/128 (16 tiles), kt = k/32 (64 tiles).
#define TILE_SH 4096   // shorts per tile

typedef __attribute__((ext_vector_type(8))) short short8;
typedef __attribute__((ext_vector_type(4))) float float4v;
typedef unsigned short ushort_t;

static __device__ __forceinline__ ushort_t f2bf(float f) {
    unsigned int u = __float_as_uint(f);
    u += 0x7fff + ((u >> 16) & 1);
    return (ushort_t)(u >> 16);
}
static __device__ __forceinline__ float bf2f(ushort_t s) {
    return __uint_as_float(((unsigned int)s) << 16);
}
__device__ __forceinline__ float silu_f(float x) { return x / (1.f + expf(-x)); }

__device__ __forceinline__ void gl_lds16(const ushort_t* g, short* l) {
    __builtin_amdgcn_global_load_lds((const __attribute__((address_space(1))) void*)g,
                                     (__attribute__((address_space(3))) void*)l, 16, 0, 0);
}

// out += p (final reduction for MODE-1 split-K=2)
__global__ __launch_bounds__(256)
void addp_kernel(float* __restrict__ out, const float* __restrict__ p, int n4)
{
    const int i = blockIdx.x * 256 + threadIdx.x;
    if (i >= n4) return;
    float4 a = ((const float4*)out)[i];
    const float4 b = ((const float4*)p)[i];
    a.x += b.x; a.y += b.y; a.z += b.z; a.w += b.w;
    ((float4*)out)[i] = a;
}

// Fused prep: z=0..4 -> weight W[z] (K x N f32) transposed to WT hi/lo TILED;
// z=5..8 -> x fp32 -> (hi,lo) TILED bf16 planes (slice z-5 of 4).
// Divergence is between blocks only (split path returns before any barrier).
__global__ __launch_bounds__(256)
void prep_kernel(const float* __restrict__ x,
                 const float* __restrict__ W0, const float* __restrict__ W1,
                 const float* __restrict__ W2, const float* __restrict__ W3,
                 const float* __restrict__ W4, ushort_t* __restrict__ wt,
                 ushort_t* __restrict__ xhi, ushort_t* __restrict__ xlo)
{
    __shared__ float t[64][65];
    const size_t PL = (size_t)HIDD * HIDD;
    const int z = blockIdx.z;

    if (z >= 5) {
        // ---- x split slice (z-5): 1024 blocks x 256 threads over PL/4 float4s
        const int i = (((z - 5) * 1024 + blockIdx.y * 32 + blockIdx.x) << 8)
                    + threadIdx.x;
        const float4 v = ((const float4*)x)[i];
        ushort4 h, l;
        h.x = f2bf(v.x); l.x = f2bf(v.x - bf2f(h.x));
        h.y = f2bf(v.y); l.y = f2bf(v.y - bf2f(h.y));
        h.z = f2bf(v.z); l.z = f2bf(v.z - bf2f(h.z));
        h.w = f2bf(v.w); l.w = f2bf(v.w - bf2f(h.w));
        const int row = i >> 9, c4 = (i & 511) * 4;   // 512 float4 per 2048-row
        const size_t off = ((size_t)((row >> 7) * 64 + (c4 >> 5))) * TILE_SH
                         + (row & 127) * 32 + (c4 & 31);
        *(ushort4*)&xhi[off] = h;
        *(ushort4*)&xlo[off] = l;
        return;
    }

    // ---- weight transpose path (z = weight index)
    const float* W = (z == 0) ? W0 : (z == 1) ? W1 : (z == 2) ? W2 : (z == 3) ? W3 : W4;
    ushort_t* Thi = wt + (size_t)z * 2 * PL;
    ushort_t* Tlo = Thi + PL;

    const int k0 = blockIdx.y * 64, n0 = blockIdx.x * 64;
    const int tx = threadIdx.x & 15, ty = threadIdx.x >> 4;
    #pragma unroll
    for (int it = 0; it < 4; it++) {
        const int k = ty + it * 16;
        const float4 v = *(const float4*)&W[(size_t)(k0 + k) * HIDD + n0 + tx * 4];
        t[k][tx * 4 + 0] = v.x; t[k][tx * 4 + 1] = v.y;
        t[k][tx * 4 + 2] = v.z; t[k][tx * 4 + 3] = v.w;
    }
    __syncthreads();
    #pragma unroll
    for (int it = 0; it < 4; it++) {
        const int n = ty + it * 16;
        ushort4 h, l; float a;
        a = t[tx * 4 + 0][n]; h.x = f2bf(a); l.x = f2bf(a - bf2f(h.x));
        a = t[tx * 4 + 1][n]; h.y = f2bf(a); l.y = f2bf(a - bf2f(h.y));
        a = t[tx * 4 + 2][n]; h.z = f2bf(a); l.z = f2bf(a - bf2f(h.z));
        a = t[tx * 4 + 3][n]; h.w = f2bf(a); l.w = f2bf(a - bf2f(h.w));
        const int nn_ = n0 + n, kk_ = k0 + tx * 4;
        const size_t off = ((size_t)((nn_ >> 7) * 64 + (kk_ >> 5))) * TILE_SH
                         + (nn_ & 127) * 32 + (kk_ & 31);
        *(ushort4*)&Thi[off] = h;
        *(ushort4*)&Tlo[off] = l;
    }
}

// Split-bf16 MFMA GEMM, 128x128 tile, BK=32, 16x16x32 MFMA, A+B in LDS.
// r13 = r11 (best-measured, 467us total): MODE 0 single-buffer 2-sync loop
// (grid 1024, 32 KB LDS, ~176us/56% MfmaUtil — the measured plateau of this
// structure across r2/r7/r11); MODE 1 dbuf stage-ahead split-K=2 (grid 512).
// Refuted variants (do NOT revisit): A-from-global (r8-r10: +35us, exposed L2
// latency), 32x32 MFMA (r6: spills), 128x256 tile (r4/r5: spills or neutral),
// MODE-1 split-K=4 @16kt (r12: +31us, amortization).
template<int MODE>
__global__ __launch_bounds__(256, 4)
void mfma_gemm(const ushort_t* __restrict__ Ahi, const ushort_t* __restrict__ Alo,
               const ushort_t* __restrict__ WT, const int* __restrict__ pos_ids,
               ushort_t* __restrict__ qhi, ushort_t* __restrict__ qlo,
               ushort_t* __restrict__ khi, ushort_t* __restrict__ klo,
               ushort_t* __restrict__ vThi, ushort_t* __restrict__ vTlo,
               float* __restrict__ gbuf, float* __restrict__ outC)
{
    // MODE 0: 4 planes x 8 KB = 32 KB single buffer.
    // MODE 1: 2 x 32 KB double buffer.
    __shared__ __align__(16) short sm[(MODE == 1) ? 32768 : 16384];

    const int tid = threadIdx.x;
    const int w = tid >> 6, L = tid & 63;
    const int qd = L >> 4, lc = L & 15;
    const int lin = blockIdx.x;
    int n0, m0, kh = 0;
    if (MODE == 0) {   // XCD-stable n-groups: XCD (lin&7 heuristic) sees n-tiles 8j..8j+7
        n0 = (((lin & 7) << 3) + ((lin >> 3) & 7)) << 7;
        m0 = (lin >> 6) << 7;
    } else {
        n0 = (lin & 15) << 7;
        m0 = ((lin >> 4) & 15) << 7;
        kh = lin >> 8;
    }
    const size_t PL = (size_t)HIDD * HIDD;

    int sel, nn;
    const ushort_t *Bhi, *Blo;
    if (MODE == 0) {
        sel = n0 >> 11; nn = n0 & 2047;
        Bhi = WT + (size_t)sel * 2 * PL; Blo = Bhi + PL;
    } else {
        sel = -1; nn = n0;
        Bhi = WT; Blo = WT + PL;
    }

    // wave w stages plane w: 0:Ahi 1:Alo 2:Bhi 3:Blo
    const ushort_t* pbase = (w == 0) ? Ahi : (w == 1) ? Alo : (w == 2) ? Bhi : Blo;
    const int rt = ((w < 2) ? m0 : nn) >> 7;
    const ushort_t* tb0 = pbase + (size_t)rt * 64 * TILE_SH + L * 8;

    const int wm = (w & 1) * 64, wn = (w >> 1) * 64;
    int aoff[4], boff[4];
    #pragma unroll
    for (int i = 0; i < 4; i++) aoff[i] = (wm + i * 16 + lc) * 32 + qd * 8;
    #pragma unroll
    for (int j = 0; j < 4; j++) boff[j] = (wn + j * 16 + lc) * 32 + qd * 8;

    float4v acc[4][4];
    #pragma unroll
    for (int i = 0; i < 4; i++)
        #pragma unroll
        for (int j = 0; j < 4; j++)
            #pragma unroll
            for (int r = 0; r < 4; r++) acc[i][j][r] = 0.f;

    const int kt0 = (MODE == 1) ? kh * 32 : 0;
    const int kt1 = (MODE == 1) ? kt0 + 32 : 64;

    if (MODE == 0) {
        // ---- single buffer, stage -> sync -> compute -> sync.
        short* ldsw = sm + w * 4096;
        for (int kt = kt0; kt < kt1; kt++) {
            const ushort_t* g = tb0 + (size_t)kt * TILE_SH;
            #pragma unroll
            for (int t = 0; t < 8; t++)
                gl_lds16(g + t * 512, ldsw + t * 512);
            __syncthreads();

            short8 bhf[4], blf[4];
            #pragma unroll
            for (int j = 0; j < 4; j++) {
                bhf[j] = *(const short8*)(sm + 8192  + boff[j]);
                blf[j] = *(const short8*)(sm + 12288 + boff[j]);
            }
            #pragma unroll
            for (int i = 0; i < 4; i++) {
                const short8 ahf = *(const short8*)(sm + aoff[i]);
                const short8 alf = *(const short8*)(sm + 4096 + aoff[i]);
                #pragma unroll
                for (int j = 0; j < 4; j++) {
                    acc[i][j] = __builtin_amdgcn_mfma_f32_16x16x32_bf16(ahf, bhf[j], acc[i][j], 0, 0, 0);
                    acc[i][j] = __builtin_amdgcn_mfma_f32_16x16x32_bf16(alf, bhf[j], acc[i][j], 0, 0, 0);
                    acc[i][j] = __builtin_amdgcn_mfma_f32_16x16x32_bf16(ahf, blf[j], acc[i][j], 0, 0, 0);
                }
            }
            __syncthreads();
        }
    } else {
        // ---- double buffer + stage-ahead, one drain per kt.
        {
            const ushort_t* g = tb0 + (size_t)kt0 * TILE_SH;
            #pragma unroll
            for (int t = 0; t < 8; t++)
                gl_lds16(g + t * 512, sm + w * 4096 + t * 512);
            asm volatile("s_waitcnt vmcnt(0)" ::: "memory");
            __builtin_amdgcn_s_barrier();
            __builtin_amdgcn_sched_barrier(0);
        }
        int cur = 0;
        for (int kt = kt0; kt < kt1; kt++) {
            const short* cb = sm + (cur << 14);
            short* nb = sm + ((cur ^ 1) << 14);
            if (kt + 1 < kt1) {     // stage NEXT tile while computing current
                const ushort_t* g = tb0 + (size_t)(kt + 1) * TILE_SH;
                #pragma unroll
                for (int t = 0; t < 8; t++)
                    gl_lds16(g + t * 512, nb + w * 4096 + t * 512);
            }
            short8 bhf[4], blf[4];
            #pragma unroll
            for (int j = 0; j < 4; j++) {
                bhf[j] = *(const short8*)(cb + 8192  + boff[j]);
                blf[j] = *(const short8*)(cb + 12288 + boff[j]);
            }
            #pragma unroll
            for (int i = 0; i < 4; i++) {
                const short8 ahf = *(const short8*)(cb + aoff[i]);
                const short8 alf = *(const short8*)(cb + 4096 + aoff[i]);
                #pragma unroll
                for (int j = 0; j < 4; j++) {
                    acc[i][j] = __builtin_amdgcn_mfma_f32_16x16x32_bf16(ahf, bhf[j], acc[i][j], 0, 0, 0);
                    acc[i][j] = __builtin_amdgcn_mfma_f32_16x16x32_bf16(alf, bhf[j], acc[i][j], 0, 0, 0);
                    acc[i][j] = __builtin_amdgcn_mfma_f32_16x16x32_bf16(ahf, blf[j], acc[i][j], 0, 0, 0);
                }
            }
            asm volatile("s_waitcnt vmcnt(0)" ::: "memory");
            __builtin_amdgcn_s_barrier();
            __builtin_amdgcn_sched_barrier(0);
            cur ^= 1;
        }
    }

    // ---- epilogue via LDS bounce; stores 16B/lane wave-contiguous.
    float* ob = (float*)sm;              // [32][132]
    const int half = w & 1;
    const int head = nn >> 7;

    // #pragma unroll REQUIRED (rule #20): runtime i would put acc in scratch
    // (r0 evidence: VGPR=64, WRITE_SIZE=3.85GB, MfmaUtil 11%).
    #pragma unroll
    for (int i = 0; i < 4; i++) {
        #pragma unroll
        for (int j = 0; j < 4; j++)
            #pragma unroll
            for (int r = 0; r < 4; r++)
                ob[(half * 16 + qd * 4 + r) * 132 + wn + j * 16 + lc] = acc[i][j][r];
        __syncthreads();

        if (MODE == 1 || sel == 3) {
            float* dst = (MODE == 1) ? (kh ? gbuf : outC) : gbuf;
            #pragma unroll
            for (int p = 0; p < 4; p++) {
                const int row = p * 8 + (tid >> 5);
                const int c = (tid & 31) * 4;
                const int grow = m0 + (row >> 4) * 64 + i * 16 + (row & 15);
                const float4 vv = *(const float4*)&ob[row * 132 + c];
                *(float4*)&dst[(size_t)grow * HIDD + nn + c] = vv;
            }
        } else if (sel == 2) {
            const int d = tid >> 1, hs = tid & 1;
            const int sbase2 = m0 + hs * 64 + i * 16;
            short8 h0, h1, l0, l1;
            #pragma unroll
            for (int sp = 0; sp < 8; sp++) {
                float a = ob[(hs * 16 + sp) * 132 + d];
                ushort_t hb = f2bf(a);
                h0[sp] = (short)hb; l0[sp] = (short)f2bf(a - bf2f(hb));
                a = ob[(hs * 16 + 8 + sp) * 132 + d];
                hb = f2bf(a);
                h1[sp] = (short)hb; l1[sp] = (short)f2bf(a - bf2f(hb));
            }
            ushort_t* dh = vThi + ((size_t)head * HD + d) * S_LEN + sbase2;
            ushort_t* dl = vTlo + ((size_t)head * HD + d) * S_LEN + sbase2;
            *(short8*)dh = h0; *(short8*)(dh + 8) = h1;
            *(short8*)dl = l0; *(short8*)(dl + 8) = l1;
        } else {
            const float sgn = (sel == 0) ? 1.f : -1.f;
            ushort_t* dhb = (sel == 0) ? qhi : khi;
            ushort_t* dlb = (sel == 0) ? qlo : klo;
            #pragma unroll
            for (int p = 0; p < 2; p++) {
                const int row = p * 16 + (tid >> 4);
                const int c8 = (tid & 15) * 8;
                const int grow = m0 + (row >> 4) * 64 + i * 16 + (row & 15);
                const float pos = (float)pos_ids[grow];
                const float pe = sgn * pos * (1.f / 512.f);
                short8 hv, lv;
                #pragma unroll
                for (int pp = 0; pp < 4; pp++) {
                    const int d = c8 + pp * 2;
                    const float v0 = ob[row * 132 + d], v1 = ob[row * 132 + d + 1];
                    const float invf = exp2f(-(float)d * (13.28771238f / 128.f));
                    float s, c_; sincosf(pos * invf, &s, &c_);
                    const float scl = exp2f(log2f(((float)d + 51.2f) * (1.f / 179.2f)) * pe);
                    const float e0 = (v0 * c_ - v1 * s) * scl;
                    const float e1 = (v1 * c_ + v0 * s) * scl;
                    const ushort_t h0 = f2bf(e0), h1 = f2bf(e1);
                    hv[pp * 2] = (short)h0;  hv[pp * 2 + 1] = (short)h1;
                    lv[pp * 2] = (short)f2bf(e0 - bf2f(h0));
                    lv[pp * 2 + 1] = (short)f2bf(e1 - bf2f(h1));
                }
                *(short8*)&dhb[((size_t)head * S_LEN + grow) * HD + c8] = hv;
                *(short8*)&dlb[((size_t)head * S_LEN + grow) * HD + c8] = lv;
            }
        }
        __syncthreads();
    }
}

// Retention core: MFMA QK^T -> decay -> P relayout -> MFMA PV -> partial osum
// to global. Triangular-workload balance (r9): work unit = (head, qb, part);
// 768 blocks = 3/CU, big-work-first, GN/silu/y-pack in gn_epilogue.
#define KROW 136
#define VROW 40
#define KH_  0
#define KL_  (32 * KROW)
#define VH_  (2 * 32 * KROW)
#define VL_  (VH_ + 128 * VROW)
#define PH_  (VH_ + 2 * 128 * VROW)
#define PLO_ (PH_ + 64 * VROW)
__global__ __launch_bounds__(256, 3)
void retention2(const ushort_t* __restrict__ qhi, const ushort_t* __restrict__ qlo,
                const ushort_t* __restrict__ khi, const ushort_t* __restrict__ klo,
                const ushort_t* __restrict__ vThi, const ushort_t* __restrict__ vTlo,
                float* __restrict__ posum)
{
    __shared__ __align__(16) short sm[24064];

    const int bx = blockIdx.x;
    const int h = bx & 15;
    const int u = bx >> 4;          // 0..47, ascending = descending work
    const int g = u / 3, r3 = u % 3;
    int qb, c0, c1, part;
    if (r3 < 2) {                   // halves of qb = 31-g (17..32 chunks each)
        qb = 31 - g; part = r3;
        const int hchunks = qb + 1;
        c0 = r3 * hchunks; c1 = c0 + hchunks;
    } else {                        // whole qb = 15-g (2..32 chunks)
        qb = 15 - g; part = 0;
        c0 = 0; c1 = 2 * (qb + 1);
    }
    const int r0 = qb * 64;
    const int tid = threadIdx.x;
    const int w = tid >> 6, L = tid & 63;
    const int qd = L >> 4, lc = L & 15;

    const float e = -3.4657359f + (float)h * ((-6.2383246f + 3.4657359f) / 15.f);
    const float lg2g = logf(1.f - expf(e)) * 1.44269504f;

    short8 qfh[4], qfl[4];
    {
        const size_t qb0 = ((size_t)h * S_LEN + r0 + w * 16 + lc) * HD + qd * 8;
        #pragma unroll
        for (int ks = 0; ks < 4; ks++) {
            qfh[ks] = *(const short8*)(qhi + qb0 + ks * 32);
            qfl[ks] = *(const short8*)(qlo + qb0 + ks * 32);
        }
    }

    float4v osum[2][4];
    #pragma unroll
    for (int mt = 0; mt < 2; mt++)
        #pragma unroll
        for (int j = 0; j < 4; j++)
            #pragma unroll
            for (int r = 0; r < 4; r++) osum[mt][j][r] = 0.f;

    const int qh_ = w >> 1, vh_ = w & 1;

    for (int ch = c0; ch < c1; ch++) {
        const int kg0 = ch * 32;
        #pragma unroll
        for (int t = 0; t < 4; t++) {
            const int c = t * 256 + tid;
            const int p = c >> 9, r = (c >> 4) & 31, qq = c & 15;
            const ushort_t* src = (p ? klo : khi) + ((size_t)h * S_LEN + kg0 + r) * HD + qq * 8;
            *(short8*)(sm + (p ? KL_ : KH_) + r * KROW + qq * 8) = *(const short8*)src;
        }
        #pragma unroll
        for (int t = 0; t < 4; t++) {
            const int c = t * 256 + tid;
            const int p = c >> 9, r = (c >> 2) & 127, qq = c & 3;
            const ushort_t* src = (p ? vTlo : vThi) + ((size_t)h * HD + r) * S_LEN + kg0 + qq * 8;
            *(short8*)(sm + (p ? VL_ : VH_) + r * VROW + qq * 8) = *(const short8*)src;
        }
        __syncthreads();

        float4v sacc[2];
        #pragma unroll
        for (int j = 0; j < 2; j++)
            #pragma unroll
            for (int r = 0; r < 4; r++) sacc[j][r] = 0.f;
        #pragma unroll
        for (int ks = 0; ks < 4; ks++) {
            #pragma unroll
            for (int j = 0; j < 2; j++) {
                const short8 bh = *(const short8*)(sm + KH_ + (j * 16 + lc) * KROW + ks * 32 + qd * 8);
                const short8 bl = *(const short8*)(sm + KL_ + (j * 16 + lc) * KROW + ks * 32 + qd * 8);
                sacc[j] = __builtin_amdgcn_mfma_f32_16x16x32_bf16(qfh[ks], bh, sacc[j], 0, 0, 0);
                sacc[j] = __builtin_amdgcn_mfma_f32_16x16x32_bf16(qfl[ks], bh, sacc[j], 0, 0, 0);
                sacc[j] = __builtin_amdgcn_mfma_f32_16x16x32_bf16(qfh[ks], bl, sacc[j], 0, 0, 0);
            }
        }
        #pragma unroll
        for (int j = 0; j < 2; j++)
            #pragma unroll
            for (int r = 0; r < 4; r++) {
                const int dq = (r0 + w * 16 + qd * 4 + r) - (kg0 + j * 16 + lc);
                const float p = (dq >= 0) ? sacc[j][r] * exp2f(lg2g * (float)dq) : 0.f;
                const ushort_t hb = f2bf(p);
                const int off = (w * 16 + qd * 4 + r) * VROW + j * 16 + lc;
                sm[PH_ + off]  = (short)hb;
                sm[PLO_ + off] = (short)f2bf(p - bf2f(hb));
            }
        __syncthreads();

        #pragma unroll
        for (int mt = 0; mt < 2; mt++) {
            const short8 pfh = *(const short8*)(sm + PH_  + (qh_ * 32 + mt * 16 + lc) * VROW + qd * 8);
            const short8 pfl = *(const short8*)(sm + PLO_ + (qh_ * 32 + mt * 16 + lc) * VROW + qd * 8);
            #pragma unroll
            for (int j = 0; j < 4; j++) {
                const short8 vfh = *(const short8*)(sm + VH_ + (vh_ * 64 + j * 16 + lc) * VROW + qd * 8);
                const short8 vfl = *(const short8*)(sm + VL_ + (vh_ * 64 + j * 16 + lc) * VROW + qd * 8);
                osum[mt][j] = __builtin_amdgcn_mfma_f32_16x16x32_bf16(pfh, vfh, osum[mt][j], 0, 0, 0);
                osum[mt][j] = __builtin_amdgcn_mfma_f32_16x16x32_bf16(pfl, vfh, osum[mt][j], 0, 0, 0);
                osum[mt][j] = __builtin_amdgcn_mfma_f32_16x16x32_bf16(pfh, vfl, osum[mt][j], 0, 0, 0);
            }
        }
        __syncthreads();
    }

    // partial osum -> global [h][qb][part][64][128] f32
    float* pdst = posum + (((size_t)(h * 32 + qb) * 2 + part) * 8192);
    #pragma unroll
    for (int mt = 0; mt < 2; mt++)
        #pragma unroll
        for (int j = 0; j < 4; j++)
            #pragma unroll
            for (int r = 0; r < 4; r++) {
                const int row = qh_ * 32 + mt * 16 + qd * 4 + r;
                const int col = vh_ * 64 + j * 16 + lc;
                pdst[row * 128 + col] = osum[mt][j][r];
            }
}

// Sum partials -> groupnorm -> silu gate -> y hi/lo TILED planes.
#define EKROW 136
__global__ __launch_bounds__(256, 2)
void gn_epilogue(const float* __restrict__ posum, const float* __restrict__ gbuf,
                 const float* __restrict__ gnw, const float* __restrict__ gnb,
                 ushort_t* __restrict__ yhi, ushort_t* __restrict__ ylo)
{
    __shared__ __align__(16) short sm[2 * 64 * EKROW];
    const int qb = blockIdx.x, h = blockIdx.y;
    const int tid = threadIdx.x;
    const int row = tid >> 2;            // 0..63
    const int cq = (tid & 3) * 32;
    const int grow = qb * 64 + row;
    const float* p0 = posum + ((size_t)(h * 32 + qb) * 2) * 8192 + row * 128;
    const float* p1 = p0 + 8192;
    const bool two = (qb >= 16);

    float v[32];
    float s1 = 0.f, s2 = 0.f;
    #pragma unroll
    for (int c = 0; c < 32; c += 4) {
        float4 a = *(const float4*)&p0[cq + c];
        if (two) {
            const float4 b = *(const float4*)&p1[cq + c];
            a.x += b.x; a.y += b.y; a.z += b.z; a.w += b.w;
        }
        v[c] = a.x; v[c + 1] = a.y; v[c + 2] = a.z; v[c + 3] = a.w;
        s1 += a.x + a.y + a.z + a.w;
        s2 += a.x * a.x + a.y * a.y + a.z * a.z + a.w * a.w;
    }
    s1 += __shfl_xor(s1, 1); s2 += __shfl_xor(s2, 1);
    s1 += __shfl_xor(s1, 2); s2 += __shfl_xor(s2, 2);
    const float mean = s1 * (1.f / 128.f);
    const float inv = 1.f / sqrtf(s2 * (1.f / 128.f) - mean * mean + 1e-5f);

    #pragma unroll
    for (int c = 0; c < 32; c++) {
        const int col = cq + c;
        const float gv = gbuf[(size_t)grow * HIDD + h * HD + col];
        const float o = ((v[c] - mean) * inv * gnw[h * HD + col] + gnb[h * HD + col])
                      * silu_f(gv);
        const ushort_t hb = f2bf(o);
        sm[row * EKROW + col] = (short)hb;
        sm[64 * EKROW + row * EKROW + col] = (short)f2bf(o - bf2f(hb));
    }
    __syncthreads();
    const int r_ = tid >> 2, cs = (tid & 3) * 32;
    const int g2 = qb * 64 + r_;
    const size_t tb = ((size_t)((g2 >> 7) * 64 + h * 4 + (tid & 3))) * TILE_SH
                    + (g2 & 127) * 32;
    #pragma unroll
    for (int c8 = 0; c8 < 4; c8++) {
        *(short8*)(yhi + tb + c8 * 8) = *(const short8*)(sm + r_ * EKROW + cs + c8 * 8);
        *(short8*)(ylo + tb + c8 * 8) = *(const short8*)(sm + 64 * EKROW + r_ * EKROW + cs + c8 * 8);
    }
}

extern "C" void kernel_launch(void* const* d_in, const int* in_sizes, int n_in,
                              void* d_out, int out_size, void* d_ws, size_t ws_size,
                              hipStream_t stream) {
    const float* x   = (const float*)d_in[0];
    const int*   pid = (const int*)d_in[1];
    const float* gnw = (const float*)d_in[7];
    const float* gnb = (const float*)d_in[8];
    float* out = (float*)d_out;
    (void)in_sizes; (void)n_in; (void)out_size; (void)ws_size;

    const size_t PL = (size_t)HIDD * HIDD;

    ushort_t* wt   = (ushort_t*)d_ws;          // 10 tiled planes = 80 MiB
    ushort_t* xhi  = wt + 10 * PL;             // tiled
    ushort_t* xlo  = xhi + PL;
    ushort_t* qhi_ = xlo + PL;                 // row-major [h][s][d]
    ushort_t* qlo_ = qhi_ + PL;
    ushort_t* khi_ = qlo_ + PL;
    ushort_t* klo_ = khi_ + PL;
    ushort_t* vThi = klo_ + PL;                // row-major [h][d][s]
    ushort_t* vTlo = vThi + PL;
    float*    gbuf = (float*)(vTlo + PL);      // row-major fp32
    ushort_t* yhi  = (ushort_t*)(gbuf + PL);   // tiled
    ushort_t* ylo  = yhi + PL;
    // MODE-1 split-K partial: reuse the x planes (dead after mfma_gemm<0>).
    float*    p1   = (float*)xhi;
    // retention partial osum (33.5 MB): wt planes 0..4 (dead after gemm<0>;
    // gemm<1> reads only wt+8PL/wt+9PL).
    float*    posum = (float*)wt;

    prep_kernel<<<dim3(32, 32, 9), 256, 0, stream>>>(x,
        (const float*)d_in[2], (const float*)d_in[3], (const float*)d_in[4],
        (const float*)d_in[5], (const float*)d_in[6], wt, xhi, xlo);

    mfma_gemm<0><<<1024, 256, 0, stream>>>(xhi, xlo, wt, pid,
        qhi_, qlo_, khi_, klo_, vThi, vTlo, gbuf, nullptr);

    retention2<<<768, 256, 0, stream>>>(qhi_, qlo_, khi_, klo_, vThi, vTlo, posum);

    gn_epilogue<<<dim3(32, 16), 256, 0, stream>>>(posum, gbuf, gnw, gnb, yhi, ylo);

    mfma_gemm<1><<<512, 256, 0, stream>>>(yhi, ylo, wt + 8 * PL, pid,
        nullptr, nullptr, nullptr, nullptr, nullptr, nullptr, p1, out);

    addp_kernel<<<(int)(PL / 4 / 256), 256, 0, stream>>>(out, p1, (int)(PL / 4));
}

// Round 14
// 462.804 us; speedup vs baseline: 1.0763x; 1.0655x over previous
//
#include <hip/hip_runtime.h>
#include <math.h>

#define S_LEN 2048
#define HIDD  2048
#define NHEAD 16
#define HD    128

// Tiled plane layout for all GEMM operands: plane = [rt][kt][128][32] bf16,
// tile = 8 KB contiguous. rt = row/128 (16 tiles), kt = k/32 (64 tiles).
#define TILE_SH 4096   // shorts per tile

typedef __attribute__((ext_vector_type(8))) short short8;
typedef __attribute__((ext_vector_type(4))) float float4v;
typedef unsigned short ushort_t;

static __device__ __forceinline__ ushort_t f2bf(float f) {
    unsigned int u = __float_as_uint(f);
    u += 0x7fff + ((u >> 16) & 1);
    return (ushort_t)(u >> 16);
}
static __device__ __forceinline__ float bf2f(ushort_t s) {
    return __uint_as_float(((unsigned int)s) << 16);
}
__device__ __forceinline__ float silu_f(float x) { return x / (1.f + expf(-x)); }

__device__ __forceinline__ void gl_lds16(const ushort_t* g, short* l) {
    __builtin_amdgcn_global_load_lds((const __attribute__((address_space(1))) void*)g,
                                     (__attribute__((address_space(3))) void*)l, 16, 0, 0);
}

// fp32 row-major -> (hi, lo) TILED bf16 planes
__global__ __launch_bounds__(256)
void split_kernel(const float* __restrict__ in, ushort_t* __restrict__ hi,
                  ushort_t* __restrict__ lo, int n4)
{
    const int i = blockIdx.x * 256 + threadIdx.x;
    if (i >= n4) return;
    const float4 v = ((const float4*)in)[i];
    ushort4 h, l;
    h.x = f2bf(v.x); l.x = f2bf(v.x - bf2f(h.x));
    h.y = f2bf(v.y); l.y = f2bf(v.y - bf2f(h.y));
    h.z = f2bf(v.z); l.z = f2bf(v.z - bf2f(h.z));
    h.w = f2bf(v.w); l.w = f2bf(v.w - bf2f(h.w));
    const int row = i >> 9, c4 = (i & 511) * 4;      // 512 float4 per 2048-row
    const size_t off = ((size_t)((row >> 7) * 64 + (c4 >> 5))) * TILE_SH
                     + (row & 127) * 32 + (c4 & 31);
    *(ushort4*)&hi[off] = h;
    *(ushort4*)&lo[off] = l;
}

// out += p (final reduction for MODE-1 split-K=2)
__global__ __launch_bounds__(256)
void addp_kernel(float* __restrict__ out, const float* __restrict__ p, int n4)
{
    const int i = blockIdx.x * 256 + threadIdx.x;
    if (i >= n4) return;
    float4 a = ((const float4*)out)[i];
    const float4 b = ((const float4*)p)[i];
    a.x += b.x; a.y += b.y; a.z += b.z; a.w += b.w;
    ((float4*)out)[i] = a;
}

// All 5 weights W (K x N f32) -> WT hi/lo (N x K bf16), TILED.
__global__ __launch_bounds__(256)
void split_transpose_all(const float* __restrict__ W0, const float* __restrict__ W1,
                         const float* __restrict__ W2, const float* __restrict__ W3,
                         const float* __restrict__ W4, ushort_t* __restrict__ wt)
{
    __shared__ float t[64][65];
    const size_t PL = (size_t)HIDD * HIDD;
    const int z = blockIdx.z;
    const float* W = (z == 0) ? W0 : (z == 1) ? W1 : (z == 2) ? W2 : (z == 3) ? W3 : W4;
    ushort_t* Thi = wt + (size_t)z * 2 * PL;
    ushort_t* Tlo = Thi + PL;

    const int k0 = blockIdx.y * 64, n0 = blockIdx.x * 64;
    const int tx = threadIdx.x & 15, ty = threadIdx.x >> 4;
    #pragma unroll
    for (int it = 0; it < 4; it++) {
        const int k = ty + it * 16;
        const float4 v = *(const float4*)&W[(size_t)(k0 + k) * HIDD + n0 + tx * 4];
        t[k][tx * 4 + 0] = v.x; t[k][tx * 4 + 1] = v.y;
        t[k][tx * 4 + 2] = v.z; t[k][tx * 4 + 3] = v.w;
    }
    __syncthreads();
    #pragma unroll
    for (int it = 0; it < 4; it++) {
        const int n = ty + it * 16;
        ushort4 h, l; float a;
        a = t[tx * 4 + 0][n]; h.x = f2bf(a); l.x = f2bf(a - bf2f(h.x));
        a = t[tx * 4 + 1][n]; h.y = f2bf(a); l.y = f2bf(a - bf2f(h.y));
        a = t[tx * 4 + 2][n]; h.z = f2bf(a); l.z = f2bf(a - bf2f(h.z));
        a = t[tx * 4 + 3][n]; h.w = f2bf(a); l.w = f2bf(a - bf2f(h.w));
        const int nn_ = n0 + n, kk_ = k0 + tx * 4;
        const size_t off = ((size_t)((nn_ >> 7) * 64 + (kk_ >> 5))) * TILE_SH
                         + (nn_ & 127) * 32 + (kk_ & 31);
        *(ushort4*)&Thi[off] = h;
        *(ushort4*)&Tlo[off] = l;
    }
}

// Split-bf16 MFMA GEMM, 128x128 tile, BK=32, 16x16x32 MFMA, A+B in LDS.
// r14 = exact r11 (best-measured, 466.7us): MODE 0 single-buffer 2-sync loop
// (grid 1024, 32 KB LDS, ~176us/56% MfmaUtil — the plateau of this structure
// across r2/r7/r11/r13); MODE 1 dbuf stage-ahead split-K=2 (grid 512).
// Refuted variants (do NOT revisit): A-from-global (r8-r10: +35us exposed L2
// latency), 32x32 MFMA (r6: spills), 128x256 tile (r4/r5: spill or neutral),
// MODE-1 split-K=4 @16kt (r12: +31us amortization), fused prep launch
// (r13: +26us — LDS reservation/ordering hurt the streaming blocks).
template<int MODE>
__global__ __launch_bounds__(256, 4)
void mfma_gemm(const ushort_t* __restrict__ Ahi, const ushort_t* __restrict__ Alo,
               const ushort_t* __restrict__ WT, const int* __restrict__ pos_ids,
               ushort_t* __restrict__ qhi, ushort_t* __restrict__ qlo,
               ushort_t* __restrict__ khi, ushort_t* __restrict__ klo,
               ushort_t* __restrict__ vThi, ushort_t* __restrict__ vTlo,
               float* __restrict__ gbuf, float* __restrict__ outC)
{
    // MODE 0: 4 planes x 8 KB = 32 KB single buffer.
    // MODE 1: 2 x 32 KB double buffer.
    __shared__ __align__(16) short sm[(MODE == 1) ? 32768 : 16384];

    const int tid = threadIdx.x;
    const int w = tid >> 6, L = tid & 63;
    const int qd = L >> 4, lc = L & 15;
    const int lin = blockIdx.x;
    int n0, m0, kh = 0;
    if (MODE == 0) {   // XCD-stable n-groups: XCD (lin&7 heuristic) sees n-tiles 8j..8j+7
        n0 = (((lin & 7) << 3) + ((lin >> 3) & 7)) << 7;
        m0 = (lin >> 6) << 7;
    } else {
        n0 = (lin & 15) << 7;
        m0 = ((lin >> 4) & 15) << 7;
        kh = lin >> 8;
    }
    const size_t PL = (size_t)HIDD * HIDD;

    int sel, nn;
    const ushort_t *Bhi, *Blo;
    if (MODE == 0) {
        sel = n0 >> 11; nn = n0 & 2047;
        Bhi = WT + (size_t)sel * 2 * PL; Blo = Bhi + PL;
    } else {
        sel = -1; nn = n0;
        Bhi = WT; Blo = WT + PL;
    }

    // wave w stages plane w: 0:Ahi 1:Alo 2:Bhi 3:Blo
    const ushort_t* pbase = (w == 0) ? Ahi : (w == 1) ? Alo : (w == 2) ? Bhi : Blo;
    const int rt = ((w < 2) ? m0 : nn) >> 7;
    const ushort_t* tb0 = pbase + (size_t)rt * 64 * TILE_SH + L * 8;

    const int wm = (w & 1) * 64, wn = (w >> 1) * 64;
    int aoff[4], boff[4];
    #pragma unroll
    for (int i = 0; i < 4; i++) aoff[i] = (wm + i * 16 + lc) * 32 + qd * 8;
    #pragma unroll
    for (int j = 0; j < 4; j++) boff[j] = (wn + j * 16 + lc) * 32 + qd * 8;

    float4v acc[4][4];
    #pragma unroll
    for (int i = 0; i < 4; i++)
        #pragma unroll
        for (int j = 0; j < 4; j++)
            #pragma unroll
            for (int r = 0; r < 4; r++) acc[i][j][r] = 0.f;

    const int kt0 = (MODE == 1) ? kh * 32 : 0;
    const int kt1 = (MODE == 1) ? kt0 + 32 : 64;

    if (MODE == 0) {
        // ---- single buffer, stage -> sync -> compute -> sync.
        short* ldsw = sm + w * 4096;
        for (int kt = kt0; kt < kt1; kt++) {
            const ushort_t* g = tb0 + (size_t)kt * TILE_SH;
            #pragma unroll
            for (int t = 0; t < 8; t++)
                gl_lds16(g + t * 512, ldsw + t * 512);
            __syncthreads();

            short8 bhf[4], blf[4];
            #pragma unroll
            for (int j = 0; j < 4; j++) {
                bhf[j] = *(const short8*)(sm + 8192  + boff[j]);
                blf[j] = *(const short8*)(sm + 12288 + boff[j]);
            }
            #pragma unroll
            for (int i = 0; i < 4; i++) {
                const short8 ahf = *(const short8*)(sm + aoff[i]);
                const short8 alf = *(const short8*)(sm + 4096 + aoff[i]);
                #pragma unroll
                for (int j = 0; j < 4; j++) {
                    acc[i][j] = __builtin_amdgcn_mfma_f32_16x16x32_bf16(ahf, bhf[j], acc[i][j], 0, 0, 0);
                    acc[i][j] = __builtin_amdgcn_mfma_f32_16x16x32_bf16(alf, bhf[j], acc[i][j], 0, 0, 0);
                    acc[i][j] = __builtin_amdgcn_mfma_f32_16x16x32_bf16(ahf, blf[j], acc[i][j], 0, 0, 0);
                }
            }
            __syncthreads();
        }
    } else {
        // ---- double buffer + stage-ahead, one drain per kt.
        {
            const ushort_t* g = tb0 + (size_t)kt0 * TILE_SH;
            #pragma unroll
            for (int t = 0; t < 8; t++)
                gl_lds16(g + t * 512, sm + w * 4096 + t * 512);
            asm volatile("s_waitcnt vmcnt(0)" ::: "memory");
            __builtin_amdgcn_s_barrier();
            __builtin_amdgcn_sched_barrier(0);
        }
        int cur = 0;
        for (int kt = kt0; kt < kt1; kt++) {
            const short* cb = sm + (cur << 14);
            short* nb = sm + ((cur ^ 1) << 14);
            if (kt + 1 < kt1) {     // stage NEXT tile while computing current
                const ushort_t* g = tb0 + (size_t)(kt + 1) * TILE_SH;
                #pragma unroll
                for (int t = 0; t < 8; t++)
                    gl_lds16(g + t * 512, nb + w * 4096 + t * 512);
            }
            short8 bhf[4], blf[4];
            #pragma unroll
            for (int j = 0; j < 4; j++) {
                bhf[j] = *(const short8*)(cb + 8192  + boff[j]);
                blf[j] = *(const short8*)(cb + 12288 + boff[j]);
            }
            #pragma unroll
            for (int i = 0; i < 4; i++) {
                const short8 ahf = *(const short8*)(cb + aoff[i]);
                const short8 alf = *(const short8*)(cb + 4096 + aoff[i]);
                #pragma unroll
                for (int j = 0; j < 4; j++) {
                    acc[i][j] = __builtin_amdgcn_mfma_f32_16x16x32_bf16(ahf, bhf[j], acc[i][j], 0, 0, 0);
                    acc[i][j] = __builtin_amdgcn_mfma_f32_16x16x32_bf16(alf, bhf[j], acc[i][j], 0, 0, 0);
                    acc[i][j] = __builtin_amdgcn_mfma_f32_16x16x32_bf16(ahf, blf[j], acc[i][j], 0, 0, 0);
                }
            }
            asm volatile("s_waitcnt vmcnt(0)" ::: "memory");
            __builtin_amdgcn_s_barrier();
            __builtin_amdgcn_sched_barrier(0);
            cur ^= 1;
        }
    }

    // ---- epilogue via LDS bounce; stores 16B/lane wave-contiguous.
    float* ob = (float*)sm;              // [32][132]
    const int half = w & 1;
    const int head = nn >> 7;

    // #pragma unroll REQUIRED (rule #20): runtime i would put acc in scratch
    // (r0 evidence: VGPR=64, WRITE_SIZE=3.85GB, MfmaUtil 11%).
    #pragma unroll
    for (int i = 0; i < 4; i++) {
        #pragma unroll
        for (int j = 0; j < 4; j++)
            #pragma unroll
            for (int r = 0; r < 4; r++)
                ob[(half * 16 + qd * 4 + r) * 132 + wn + j * 16 + lc] = acc[i][j][r];
        __syncthreads();

        if (MODE == 1 || sel == 3) {
            float* dst = (MODE == 1) ? (kh ? gbuf : outC) : gbuf;
            #pragma unroll
            for (int p = 0; p < 4; p++) {
                const int row = p * 8 + (tid >> 5);
                const int c = (tid & 31) * 4;
                const int grow = m0 + (row >> 4) * 64 + i * 16 + (row & 15);
                const float4 vv = *(const float4*)&ob[row * 132 + c];
                *(float4*)&dst[(size_t)grow * HIDD + nn + c] = vv;
            }
        } else if (sel == 2) {
            const int d = tid >> 1, hs = tid & 1;
            const int sbase2 = m0 + hs * 64 + i * 16;
            short8 h0, h1, l0, l1;
            #pragma unroll
            for (int sp = 0; sp < 8; sp++) {
                float a = ob[(hs * 16 + sp) * 132 + d];
                ushort_t hb = f2bf(a);
                h0[sp] = (short)hb; l0[sp] = (short)f2bf(a - bf2f(hb));
                a = ob[(hs * 16 + 8 + sp) * 132 + d];
                hb = f2bf(a);
                h1[sp] = (short)hb; l1[sp] = (short)f2bf(a - bf2f(hb));
            }
            ushort_t* dh = vThi + ((size_t)head * HD + d) * S_LEN + sbase2;
            ushort_t* dl = vTlo + ((size_t)head * HD + d) * S_LEN + sbase2;
            *(short8*)dh = h0; *(short8*)(dh + 8) = h1;
            *(short8*)dl = l0; *(short8*)(dl + 8) = l1;
        } else {
            const float sgn = (sel == 0) ? 1.f : -1.f;
            ushort_t* dhb = (sel == 0) ? qhi : khi;
            ushort_t* dlb = (sel == 0) ? qlo : klo;
            #pragma unroll
            for (int p = 0; p < 2; p++) {
                const int row = p * 16 + (tid >> 4);
                const int c8 = (tid & 15) * 8;
                const int grow = m0 + (row >> 4) * 64 + i * 16 + (row & 15);
                const float pos = (float)pos_ids[grow];
                const float pe = sgn * pos * (1.f / 512.f);
                short8 hv, lv;
                #pragma unroll
                for (int pp = 0; pp < 4; pp++) {
                    const int d = c8 + pp * 2;
                    const float v0 = ob[row * 132 + d], v1 = ob[row * 132 + d + 1];
                    const float invf = exp2f(-(float)d * (13.28771238f / 128.f));
                    float s, c_; sincosf(pos * invf, &s, &c_);
                    const float scl = exp2f(log2f(((float)d + 51.2f) * (1.f / 179.2f)) * pe);
                    const float e0 = (v0 * c_ - v1 * s) * scl;
                    const float e1 = (v1 * c_ + v0 * s) * scl;
                    const ushort_t h0 = f2bf(e0), h1 = f2bf(e1);
                    hv[pp * 2] = (short)h0;  hv[pp * 2 + 1] = (short)h1;
                    lv[pp * 2] = (short)f2bf(e0 - bf2f(h0));
                    lv[pp * 2 + 1] = (short)f2bf(e1 - bf2f(h1));
                }
                *(short8*)&dhb[((size_t)head * S_LEN + grow) * HD + c8] = hv;
                *(short8*)&dlb[((size_t)head * S_LEN + grow) * HD + c8] = lv;
            }
        }
        __syncthreads();
    }
}

// Retention core: MFMA QK^T -> decay -> P relayout -> MFMA PV -> partial osum
// to global. Triangular-workload balance (r9): work unit = (head, qb, part);
// 768 blocks = 3/CU, big-work-first, GN/silu/y-pack in gn_epilogue.
#define KROW 136
#define VROW 40
#define KH_  0
#define KL_  (32 * KROW)
#define VH_  (2 * 32 * KROW)
#define VL_  (VH_ + 128 * VROW)
#define PH_  (VH_ + 2 * 128 * VROW)
#define PLO_ (PH_ + 64 * VROW)
__global__ __launch_bounds__(256, 3)
void retention2(const ushort_t* __restrict__ qhi, const ushort_t* __restrict__ qlo,
                const ushort_t* __restrict__ khi, const ushort_t* __restrict__ klo,
                const ushort_t* __restrict__ vThi, const ushort_t* __restrict__ vTlo,
                float* __restrict__ posum)
{
    __shared__ __align__(16) short sm[24064];

    const int bx = blockIdx.x;
    const int h = bx & 15;
    const int u = bx >> 4;          // 0..47, ascending = descending work
    const int g = u / 3, r3 = u % 3;
    int qb, c0, c1, part;
    if (r3 < 2) {                   // halves of qb = 31-g (17..32 chunks each)
        qb = 31 - g; part = r3;
        const int hchunks = qb + 1;
        c0 = r3 * hchunks; c1 = c0 + hchunks;
    } else {                        // whole qb = 15-g (2..32 chunks)
        qb = 15 - g; part = 0;
        c0 = 0; c1 = 2 * (qb + 1);
    }
    const int r0 = qb * 64;
    const int tid = threadIdx.x;
    const int w = tid >> 6, L = tid & 63;
    const int qd = L >> 4, lc = L & 15;

    const float e = -3.4657359f + (float)h * ((-6.2383246f + 3.4657359f) / 15.f);
    const float lg2g = logf(1.f - expf(e)) * 1.44269504f;

    short8 qfh[4], qfl[4];
    {
        const size_t qb0 = ((size_t)h * S_LEN + r0 + w * 16 + lc) * HD + qd * 8;
        #pragma unroll
        for (int ks = 0; ks < 4; ks++) {
            qfh[ks] = *(const short8*)(qhi + qb0 + ks * 32);
            qfl[ks] = *(const short8*)(qlo + qb0 + ks * 32);
        }
    }

    float4v osum[2][4];
    #pragma unroll
    for (int mt = 0; mt < 2; mt++)
        #pragma unroll
        for (int j = 0; j < 4; j++)
            #pragma unroll
            for (int r = 0; r < 4; r++) osum[mt][j][r] = 0.f;

    const int qh_ = w >> 1, vh_ = w & 1;

    for (int ch = c0; ch < c1; ch++) {
        const int kg0 = ch * 32;
        #pragma unroll
        for (int t = 0; t < 4; t++) {
            const int c = t * 256 + tid;
            const int p = c >> 9, r = (c >> 4) & 31, qq = c & 15;
            const ushort_t* src = (p ? klo : khi) + ((size_t)h * S_LEN + kg0 + r) * HD + qq * 8;
            *(short8*)(sm + (p ? KL_ : KH_) + r * KROW + qq * 8) = *(const short8*)src;
        }
        #pragma unroll
        for (int t = 0; t < 4; t++) {
            const int c = t * 256 + tid;
            const int p = c >> 9, r = (c >> 2) & 127, qq = c & 3;
            const ushort_t* src = (p ? vTlo : vThi) + ((size_t)h * HD + r) * S_LEN + kg0 + qq * 8;
            *(short8*)(sm + (p ? VL_ : VH_) + r * VROW + qq * 8) = *(const short8*)src;
        }
        __syncthreads();

        float4v sacc[2];
        #pragma unroll
        for (int j = 0; j < 2; j++)
            #pragma unroll
            for (int r = 0; r < 4; r++) sacc[j][r] = 0.f;
        #pragma unroll
        for (int ks = 0; ks < 4; ks++) {
            #pragma unroll
            for (int j = 0; j < 2; j++) {
                const short8 bh = *(const short8*)(sm + KH_ + (j * 16 + lc) * KROW + ks * 32 + qd * 8);
                const short8 bl = *(const short8*)(sm + KL_ + (j * 16 + lc) * KROW + ks * 32 + qd * 8);
                sacc[j] = __builtin_amdgcn_mfma_f32_16x16x32_bf16(qfh[ks], bh, sacc[j], 0, 0, 0);
                sacc[j] = __builtin_amdgcn_mfma_f32_16x16x32_bf16(qfl[ks], bh, sacc[j], 0, 0, 0);
                sacc[j] = __builtin_amdgcn_mfma_f32_16x16x32_bf16(qfh[ks], bl, sacc[j], 0, 0, 0);
            }
        }
        #pragma unroll
        for (int j = 0; j < 2; j++)
            #pragma unroll
            for (int r = 0; r < 4; r++) {
                const int dq = (r0 + w * 16 + qd * 4 + r) - (kg0 + j * 16 + lc);
                const float p = (dq >= 0) ? sacc[j][r] * exp2f(lg2g * (float)dq) : 0.f;
                const ushort_t hb = f2bf(p);
                const int off = (w * 16 + qd * 4 + r) * VROW + j * 16 + lc;
                sm[PH_ + off]  = (short)hb;
                sm[PLO_ + off] = (short)f2bf(p - bf2f(hb));
            }
        __syncthreads();

        #pragma unroll
        for (int mt = 0; mt < 2; mt++) {
            const short8 pfh = *(const short8*)(sm + PH_  + (qh_ * 32 + mt * 16 + lc) * VROW + qd * 8);
            const short8 pfl = *(const short8*)(sm + PLO_ + (qh_ * 32 + mt * 16 + lc) * VROW + qd * 8);
            #pragma unroll
            for (int j = 0; j < 4; j++) {
                const short8 vfh = *(const short8*)(sm + VH_ + (vh_ * 64 + j * 16 + lc) * VROW + qd * 8);
                const short8 vfl = *(const short8*)(sm + VL_ + (vh_ * 64 + j * 16 + lc) * VROW + qd * 8);
                osum[mt][j] = __builtin_amdgcn_mfma_f32_16x16x32_bf16(pfh, vfh, osum[mt][j], 0, 0, 0);
                osum[mt][j] = __builtin_amdgcn_mfma_f32_16x16x32_bf16(pfl, vfh, osum[mt][j], 0, 0, 0);
                osum[mt][j] = __builtin_amdgcn_mfma_f32_16x16x32_bf16(pfh, vfl, osum[mt][j], 0, 0, 0);
            }
        }
        __syncthreads();
    }

    // partial osum -> global [h][qb][part][64][128] f32
    float* pdst = posum + (((size_t)(h * 32 + qb) * 2 + part) * 8192);
    #pragma unroll
    for (int mt = 0; mt < 2; mt++)
        #pragma unroll
        for (int j = 0; j < 4; j++)
            #pragma unroll
            for (int r = 0; r < 4; r++) {
                const int row = qh_ * 32 + mt * 16 + qd * 4 + r;
                const int col = vh_ * 64 + j * 16 + lc;
                pdst[row * 128 + col] = osum[mt][j][r];
            }
}

// Sum partials -> groupnorm -> silu gate -> y hi/lo TILED planes.
#define EKROW 136
__global__ __launch_bounds__(256, 2)
void gn_epilogue(const float* __restrict__ posum, const float* __restrict__ gbuf,
                 const float* __restrict__ gnw, const float* __restrict__ gnb,
                 ushort_t* __restrict__ yhi, ushort_t* __restrict__ ylo)
{
    __shared__ __align__(16) short sm[2 * 64 * EKROW];
    const int qb = blockIdx.x, h = blockIdx.y;
    const int tid = threadIdx.x;
    const int row = tid >> 2;            // 0..63
    const int cq = (tid & 3) * 32;
    const int grow = qb * 64 + row;
    const float* p0 = posum + ((size_t)(h * 32 + qb) * 2) * 8192 + row * 128;
    const float* p1 = p0 + 8192;
    const bool two = (qb >= 16);

    float v[32];
    float s1 = 0.f, s2 = 0.f;
    #pragma unroll
    for (int c = 0; c < 32; c += 4) {
        float4 a = *(const float4*)&p0[cq + c];
        if (two) {
            const float4 b = *(const float4*)&p1[cq + c];
            a.x += b.x; a.y += b.y; a.z += b.z; a.w += b.w;
        }
        v[c] = a.x; v[c + 1] = a.y; v[c + 2] = a.z; v[c + 3] = a.w;
        s1 += a.x + a.y + a.z + a.w;
        s2 += a.x * a.x + a.y * a.y + a.z * a.z + a.w * a.w;
    }
    s1 += __shfl_xor(s1, 1); s2 += __shfl_xor(s2, 1);
    s1 += __shfl_xor(s1, 2); s2 += __shfl_xor(s2, 2);
    const float mean = s1 * (1.f / 128.f);
    const float inv = 1.f / sqrtf(s2 * (1.f / 128.f) - mean * mean + 1e-5f);

    #pragma unroll
    for (int c = 0; c < 32; c++) {
        const int col = cq + c;
        const float gv = gbuf[(size_t)grow * HIDD + h * HD + col];
        const float o = ((v[c] - mean) * inv * gnw[h * HD + col] + gnb[h * HD + col])
                      * silu_f(gv);
        const ushort_t hb = f2bf(o);
        sm[row * EKROW + col] = (short)hb;
        sm[64 * EKROW + row * EKROW + col] = (short)f2bf(o - bf2f(hb));
    }
    __syncthreads();
    const int r_ = tid >> 2, cs = (tid & 3) * 32;
    const int g2 = qb * 64 + r_;
    const size_t tb = ((size_t)((g2 >> 7) * 64 + h * 4 + (tid & 3))) * TILE_SH
                    + (g2 & 127) * 32;
    #pragma unroll
    for (int c8 = 0; c8 < 4; c8++) {
        *(short8*)(yhi + tb + c8 * 8) = *(const short8*)(sm + r_ * EKROW + cs + c8 * 8);
        *(short8*)(ylo + tb + c8 * 8) = *(const short8*)(sm + 64 * EKROW + r_ * EKROW + cs + c8 * 8);
    }
}

extern "C" void kernel_launch(void* const* d_in, const int* in_sizes, int n_in,
                              void* d_out, int out_size, void* d_ws, size_t ws_size,
                              hipStream_t stream) {
    const float* x   = (const float*)d_in[0];
    const int*   pid = (const int*)d_in[1];
    const float* gnw = (const float*)d_in[7];
    const float* gnb = (const float*)d_in[8];
    float* out = (float*)d_out;
    (void)in_sizes; (void)n_in; (void)out_size; (void)ws_size;

    const size_t PL = (size_t)HIDD * HIDD;

    ushort_t* wt   = (ushort_t*)d_ws;          // 10 tiled planes = 80 MiB
    ushort_t* xhi  = wt + 10 * PL;             // tiled
    ushort_t* xlo  = xhi + PL;
    ushort_t* qhi_ = xlo + PL;                 // row-major [h][s][d]
    ushort_t* qlo_ = qhi_ + PL;
    ushort_t* khi_ = qlo_ + PL;
    ushort_t* klo_ = khi_ + PL;
    ushort_t* vThi = klo_ + PL;                // row-major [h][d][s]
    ushort_t* vTlo = vThi + PL;
    float*    gbuf = (float*)(vTlo + PL);      // row-major fp32
    ushort_t* yhi  = (ushort_t*)(gbuf + PL);   // tiled
    ushort_t* ylo  = yhi + PL;
    // MODE-1 split-K partial: reuse the x planes (dead after mfma_gemm<0>).
    float*    p1   = (float*)xhi;
    // retention partial osum (33.5 MB): wt planes 0..4 (dead after gemm<0>;
    // gemm<1> reads only wt+8PL/wt+9PL).
    float*    posum = (float*)wt;

    split_kernel<<<(int)(PL / 4 / 256), 256, 0, stream>>>(x, xhi, xlo, (int)(PL / 4));
    split_transpose_all<<<dim3(32, 32, 5), 256, 0, stream>>>(
        (const float*)d_in[2], (const float*)d_in[3], (const float*)d_in[4],
        (const float*)d_in[5], (const float*)d_in[6], wt);

    mfma_gemm<0><<<1024, 256, 0, stream>>>(xhi, xlo, wt, pid,
        qhi_, qlo_, khi_, klo_, vThi, vTlo, gbuf, nullptr);

    retention2<<<768, 256, 0, stream>>>(qhi_, qlo_, khi_, klo_, vThi, vTlo, posum);

    gn_epilogue<<<dim3(32, 16), 256, 0, stream>>>(posum, gbuf, gnw, gnb, yhi, ylo);

    mfma_gemm<1><<<512, 256, 0, stream>>>(yhi, ylo, wt + 8 * PL, pid,
        nullptr, nullptr, nullptr, nullptr, nullptr, nullptr, p1, out);

    addp_kernel<<<(int)(PL / 4 / 256), 256, 0, stream>>>(out, p1, (int)(PL / 4));
}